// Round 8
// baseline (442.334 us; speedup 1.0000x reference)
//
#include <hip/hip_runtime.h>
#include <hip/hip_bf16.h>

// Problem constants
#define BB   128
#define NN   196
#define MM   (BB*NN)      // 25088
#define ENC  2048
#define ATT  512
#define DEC  512
#define BK   32
#define KSTEPS (ENC/BK)   // 64
#define BM   128          // gemm m-rows per block
#define BA   256          // gemm a-cols per block

using f32x4 = __attribute__((ext_vector_type(4))) float;
using s16x8 = __attribute__((ext_vector_type(8))) short;
using u16x4 = __attribute__((ext_vector_type(4))) unsigned short;
using u16x8 = __attribute__((ext_vector_type(8))) unsigned short;

__device__ __forceinline__ short f2bf(float f) {
    union { __hip_bfloat16 h; short s; } u;
    u.h = __float2bfloat16(f);
    return u.s;
}
__device__ __forceinline__ float bf2f(unsigned short u) {
    union { unsigned int i; float f; } v;
    v.i = ((unsigned int)u) << 16;
    return v.f;
}

// LDS byte offset (32-bit) of a generic pointer into __shared__
__device__ __forceinline__ unsigned lds_addr(void* p) {
    return (unsigned)(unsigned long long)(__attribute__((address_space(3))) void*)p;
}

// inline-asm ds_read_b128: keeps the compiler's LDS-dependency tracker from
// inserting a vmcnt(0) drain before fragment reads (R1 regression cause).
// "=&v" early-clobber: dest tuple must not overlap the live address VGPR.
#define DSR(dst, base, imm) \
    asm volatile("ds_read_b128 %0, %1 offset:" #imm : "=&v"(dst) : "v"(base))

// ---------------------------------------------------------------------------
// k0a: transpose+convert W_enc [2048][512] f32 -> Wt [512][2048] bf16
// ---------------------------------------------------------------------------
__global__ void transpose_convert_kernel(const float* __restrict__ W,
                                         unsigned short* __restrict__ Wt) {
    __shared__ float tile[32][33];
    const int a0 = blockIdx.x * 32;
    const int k0 = blockIdx.y * 32;
    const int tx = threadIdx.x & 31, ty = threadIdx.x >> 5;
    #pragma unroll
    for (int i = 0; i < 32; i += 8)
        tile[ty + i][tx] = W[(size_t)(k0 + ty + i) * ATT + a0 + tx];
    __syncthreads();
    #pragma unroll
    for (int i = 0; i < 32; i += 8) {
        union { __hip_bfloat16 h; unsigned short u; } v;
        v.h = __float2bfloat16(tile[tx][ty + i]);
        Wt[(size_t)(a0 + ty + i) * ENC + k0 + tx] = v.u;
    }
}

// ---------------------------------------------------------------------------
// k0c: convert encoder_out fp32 -> bf16 (row per block; 256 thr x 8 elem)
// ---------------------------------------------------------------------------
__global__ __launch_bounds__(256)
void enc_cvt_kernel(const float* __restrict__ enc,
                    unsigned short* __restrict__ encb) {
    const size_t row = blockIdx.x;
    const int t = threadIdx.x;
    const float* in = enc + row * ENC + t * 8;
    f32x4 a = *(const f32x4*)in;
    f32x4 b = *(const f32x4*)(in + 4);
    u16x8 o;
    #pragma unroll
    for (int j = 0; j < 4; ++j) {
        o[j]     = (unsigned short)f2bf(a[j]);
        o[4 + j] = (unsigned short)f2bf(b[j]);
    }
    *(u16x8*)(encb + row * ENC + t * 8) = o;
}

// ---------------------------------------------------------------------------
// k0b: att2[b][a] = dec[b] @ W_dec[:,a] + b_dec[a] + b_enc[a]
// ---------------------------------------------------------------------------
__global__ void att2_kernel(const float* __restrict__ dec,
                            const float* __restrict__ Wd,
                            const float* __restrict__ bd,
                            const float* __restrict__ benc,
                            float* __restrict__ att2) {
    const int b  = blockIdx.x;
    const int c0 = blockIdx.y * 64;
    const int t  = threadIdx.x;
    const int cl = t & 63, kg = t >> 6;
    __shared__ float sdec[DEC];
    __shared__ float red[4][64];
    sdec[t]       = dec[b * DEC + t];
    sdec[t + 256] = dec[b * DEC + t + 256];
    __syncthreads();
    float acc = 0.f;
    const float* wp = Wd + c0 + cl;
    #pragma unroll 8
    for (int k = kg * 128; k < kg * 128 + 128; ++k)
        acc += sdec[k] * wp[(size_t)k * ATT];
    red[kg][cl] = acc;
    __syncthreads();
    if (t < 64) {
        float s = red[0][t] + red[1][t] + red[2][t] + red[3][t];
        att2[b * ATT + c0 + t] = s + bd[c0 + t] + benc[c0 + t];
    }
}

// ---------------------------------------------------------------------------
// k1 MAIN: fused GEMM + bias + relu + dot(W_full) -> e_part[2][MM]
//   R(polish-7 = polish-6 resubmit, DSR hardened to "=&v"): counted-vmcnt
//   2-phase pipeline (T3+T4 minimum, m201 primitives). R6's __syncthreads
//   dbuf was NEUTRAL because syncthreads drains vmcnt(0) -> the
//   just-issued prefetch is waited on anyway. Here: raw s_barrier (no
//   drain) + asm "s_waitcnt vmcnt(3)" (each stage = 3 global_load_lds
//   per wave; next tile's 3 STAY IN FLIGHT across the barrier) + asm
//   ds_read_b128 (compiler can't re-insert vmcnt(0) before LDS reads) +
//   lgkmcnt(0)+sched_barrier(0) before MFMAs (rule #18). Per K-step:
//   stage(next) -> vmcnt(3) -> barrier -> 8 ds_read + 16 MFMA -> barrier
//   (protects buffer overwritten next step).
//   Config = R4 winner: 512 thr, 8 waves 2m x 4a, 4x4 frags/wave,
//   BM=128/BA=256/BK=32, fragment-linear LDS (conflicts 0). LDS 48.5 KB,
//   2 blocks/CU. Grid (2,196).
// ---------------------------------------------------------------------------
__global__ __launch_bounds__(512, 4)
void gemm_bf16_kernel(const unsigned short* __restrict__ encb,
                      const unsigned short* __restrict__ Wt,
                      const float* __restrict__ att2,
                      const float* __restrict__ Wf,
                      float* __restrict__ e_part) {
    // fragment-linear: A slot = mi*64 + lane (mi 0..7), 16 B/slot
    //                  B slot = ni*64 + lane (ni 0..15)
    __shared__ unsigned short sA0[512 * 8];     // 8 KB
    __shared__ unsigned short sA1[512 * 8];     // 8 KB
    __shared__ unsigned short sB0[1024 * 8];    // 16 KB
    __shared__ unsigned short sB1[1024 * 8];    // 16 KB
    __shared__ float e_sm[BM];

    const int t    = threadIdx.x;      // 0..511
    const int lane = t & 63;
    const int w    = t >> 6;           // 0..7
    const int wm   = w >> 2;           // 0..1  (m wave-row)
    const int wa   = w & 3;            // 0..3  (a wave-col)
    const int aBlk  = blockIdx.x;      // 0..1
    const int mBase = blockIdx.y * BM; // 196 tiles
    const int aBase = aBlk * BA;
    const int r = lane & 15, q = lane >> 4;

    if (t < BM) e_sm[t] = 0.f;         // visible long before epilogue use

    // --- staging sources (pre-swizzled global addresses, fragment order) ---
    // A: thread t -> slot t: mi=t>>6, row=mi*16+(t&15), kchunk=((t>>4)&3)*8
    const unsigned short* gA =
        encb + (size_t)(mBase + ((t >> 6) << 4) + (t & 15)) * ENC + ((t >> 4) & 3) * 8;
    // B: slot s=i*512+t: ni=s>>6, row=ni*16+(s&15), kchunk=((s>>4)&3)*8
    const unsigned short* gB[2];
    #pragma unroll
    for (int i = 0; i < 2; ++i) {
        int s = i * 512 + t;
        gB[i] = Wt + (size_t)(aBase + ((s >> 6) << 4) + (s & 15)) * ENC + ((s >> 4) & 3) * 8;
    }

    // per-thread LDS read bases (byte offsets): frag block (wm*4+mi) / (wa*4+ni)
    const unsigned a0base = lds_addr(sA0) + (unsigned)(wm * 4096 + lane * 16);
    const unsigned a1base = lds_addr(sA1) + (unsigned)(wm * 4096 + lane * 16);
    const unsigned b0base = lds_addr(sB0) + (unsigned)(wa * 4096 + lane * 16);
    const unsigned b1base = lds_addr(sB1) + (unsigned)(wa * 4096 + lane * 16);

    f32x4 acc[4][4] = {};

    auto stage = [&](unsigned short* bA, unsigned short* bB, int ks) {
        __builtin_amdgcn_global_load_lds(
            (const __attribute__((address_space(1))) void*)(gA + (size_t)ks * BK),
            (__attribute__((address_space(3))) void*)((char*)bA + t * 16),
            16, 0, 0);
        #pragma unroll
        for (int i = 0; i < 2; ++i)
            __builtin_amdgcn_global_load_lds(
                (const __attribute__((address_space(1))) void*)(gB[i] + (size_t)ks * BK),
                (__attribute__((address_space(3))) void*)((char*)bB + (i * 512 + t) * 16),
                16, 0, 0);
    };

    auto compute = [&](unsigned abase, unsigned bbase) {
        s16x8 af0, af1, af2, af3, bf0, bf1, bf2, bf3;
        DSR(af0, abase, 0);
        DSR(af1, abase, 1024);
        DSR(af2, abase, 2048);
        DSR(af3, abase, 3072);
        DSR(bf0, bbase, 0);
        DSR(bf1, bbase, 1024);
        DSR(bf2, bbase, 2048);
        DSR(bf3, bbase, 3072);
        asm volatile("s_waitcnt lgkmcnt(0)" ::: "memory");
        __builtin_amdgcn_sched_barrier(0);
        acc[0][0] = __builtin_amdgcn_mfma_f32_16x16x32_bf16(af0, bf0, acc[0][0], 0, 0, 0);
        acc[0][1] = __builtin_amdgcn_mfma_f32_16x16x32_bf16(af0, bf1, acc[0][1], 0, 0, 0);
        acc[0][2] = __builtin_amdgcn_mfma_f32_16x16x32_bf16(af0, bf2, acc[0][2], 0, 0, 0);
        acc[0][3] = __builtin_amdgcn_mfma_f32_16x16x32_bf16(af0, bf3, acc[0][3], 0, 0, 0);
        acc[1][0] = __builtin_amdgcn_mfma_f32_16x16x32_bf16(af1, bf0, acc[1][0], 0, 0, 0);
        acc[1][1] = __builtin_amdgcn_mfma_f32_16x16x32_bf16(af1, bf1, acc[1][1], 0, 0, 0);
        acc[1][2] = __builtin_amdgcn_mfma_f32_16x16x32_bf16(af1, bf2, acc[1][2], 0, 0, 0);
        acc[1][3] = __builtin_amdgcn_mfma_f32_16x16x32_bf16(af1, bf3, acc[1][3], 0, 0, 0);
        acc[2][0] = __builtin_amdgcn_mfma_f32_16x16x32_bf16(af2, bf0, acc[2][0], 0, 0, 0);
        acc[2][1] = __builtin_amdgcn_mfma_f32_16x16x32_bf16(af2, bf1, acc[2][1], 0, 0, 0);
        acc[2][2] = __builtin_amdgcn_mfma_f32_16x16x32_bf16(af2, bf2, acc[2][2], 0, 0, 0);
        acc[2][3] = __builtin_amdgcn_mfma_f32_16x16x32_bf16(af2, bf3, acc[2][3], 0, 0, 0);
        acc[3][0] = __builtin_amdgcn_mfma_f32_16x16x32_bf16(af3, bf0, acc[3][0], 0, 0, 0);
        acc[3][1] = __builtin_amdgcn_mfma_f32_16x16x32_bf16(af3, bf1, acc[3][1], 0, 0, 0);
        acc[3][2] = __builtin_amdgcn_mfma_f32_16x16x32_bf16(af3, bf2, acc[3][2], 0, 0, 0);
        acc[3][3] = __builtin_amdgcn_mfma_f32_16x16x32_bf16(af3, bf3, acc[3][3], 0, 0, 0);
    };

    // counted-vmcnt 2-phase pipeline. In-flight: 3 loads/wave per stage.
    // stage(next) -> vmcnt(3) [cur's 3 done, next's 3 in flight] -> barrier
    // -> compute(cur) -> barrier [all waves done reading cur before it is
    // overwritten next step].
    stage(sA0, sB0, 0);
    #pragma unroll 1
    for (int ks = 0; ks < KSTEPS - 2; ks += 2) {
        stage(sA1, sB1, ks + 1);
        asm volatile("s_waitcnt vmcnt(3)" ::: "memory");
        __builtin_amdgcn_s_barrier();
        compute(a0base, b0base);
        __builtin_amdgcn_s_barrier();
        stage(sA0, sB0, ks + 2);
        asm volatile("s_waitcnt vmcnt(3)" ::: "memory");
        __builtin_amdgcn_s_barrier();
        compute(a1base, b1base);
        __builtin_amdgcn_s_barrier();
    }
    // epilogue: steps KSTEPS-2 (in sA0/sB0, in flight) and KSTEPS-1
    stage(sA1, sB1, KSTEPS - 1);
    asm volatile("s_waitcnt vmcnt(3)" ::: "memory");
    __builtin_amdgcn_s_barrier();
    compute(a0base, b0base);
    __builtin_amdgcn_s_barrier();
    asm volatile("s_waitcnt vmcnt(0)" ::: "memory");
    __builtin_amdgcn_s_barrier();
    compute(a1base, b1base);

    // --- epilogue: e contribution = sum_a relu(att1 + att2) * Wf ---
    float wfv[4];
    #pragma unroll
    for (int ni = 0; ni < 4; ++ni)
        wfv[ni] = Wf[aBase + wa * 64 + ni * 16 + r];

    #pragma unroll
    for (int mi = 0; mi < 4; ++mi) {
        #pragma unroll
        for (int reg = 0; reg < 4; ++reg) {
            int lrow = wm * 64 + mi * 16 + q * 4 + reg;  // C/D: row=(lane>>4)*4+reg
            int gm = mBase + lrow;
            int b = gm / NN;
            const float* a2 = att2 + b * ATT + aBase + wa * 64;
            float rs = 0.f;
            #pragma unroll
            for (int ni = 0; ni < 4; ++ni) {
                float v = acc[mi][ni][reg] + a2[ni * 16 + r];  // col = lane&15
                rs += fmaxf(v, 0.f) * wfv[ni];
            }
            rs += __shfl_xor(rs, 1);
            rs += __shfl_xor(rs, 2);
            rs += __shfl_xor(rs, 4);
            rs += __shfl_xor(rs, 8);
            if (r == 0) atomicAdd(&e_sm[lrow], rs);
        }
    }
    __syncthreads();
    if (t < BM)
        e_part[(size_t)aBlk * MM + mBase + t] = e_sm[t];
}

// ---------------------------------------------------------------------------
// k1 FALLBACK (R4): 64m x 128a fp32-A gemm -> e_part[4][MM]
// ---------------------------------------------------------------------------
__global__ __launch_bounds__(256, 5)
void gemm_e_kernel(const float* __restrict__ enc,
                   const unsigned short* __restrict__ Wt,
                   const float* __restrict__ att2,
                   const float* __restrict__ Wf,
                   float* __restrict__ e_part) {
    __shared__ float sA[64 * 32];
    __shared__ unsigned short sB[128 * 32];
    __shared__ float e_sm[64];

    const int t    = threadIdx.x;
    const int lane = t & 63;
    const int w    = t >> 6;
    const int aBlk  = blockIdx.x;
    const int mBase = blockIdx.y * 64;
    const int aBase = aBlk * 128;
    const int r = lane & 15, q = lane >> 4;

    const float* gA[2];
    #pragma unroll
    for (int i = 0; i < 2; ++i) {
        int s = i * 256 + t;
        int row = s >> 3, ck = s & 7;
        int g = ck ^ (row & 7);
        gA[i] = enc + (size_t)(mBase + row) * ENC + g * 4;
    }
    const unsigned short* gB[2];
    #pragma unroll
    for (int i = 0; i < 2; ++i) {
        int s = i * 256 + t;
        int row = s >> 2, ck = s & 3;
        int g = ck ^ ((row & 3) ^ ((row >> 2) & 3));
        gB[i] = Wt + (size_t)(aBase + row) * ENC + g * 8;
    }

    int offA[4][2];
    #pragma unroll
    for (int mi = 0; mi < 4; ++mi) {
        int row = mi * 16 + r;
        offA[mi][0] = row * 128 + ((2 * q)     ^ (row & 7)) * 16;
        offA[mi][1] = row * 128 + ((2 * q + 1) ^ (row & 7)) * 16;
    }
    int offB[2];
    #pragma unroll
    for (int ni = 0; ni < 2; ++ni) {
        int col = w * 32 + ni * 16 + r;
        offB[ni] = col * 64 + (q ^ ((col & 3) ^ ((col >> 2) & 3))) * 16;
    }

    f32x4 acc[4][2] = {};

    #pragma unroll 1
    for (int ks = 0; ks < KSTEPS; ++ks) {
        #pragma unroll
        for (int i = 0; i < 2; ++i)
            __builtin_amdgcn_global_load_lds(
                (const __attribute__((address_space(1))) void*)(gA[i] + (size_t)ks * BK),
                (__attribute__((address_space(3))) void*)((char*)sA + (i * 256 + w * 64) * 16),
                16, 0, 0);
        #pragma unroll
        for (int i = 0; i < 2; ++i)
            __builtin_amdgcn_global_load_lds(
                (const __attribute__((address_space(1))) void*)(gB[i] + (size_t)ks * BK),
                (__attribute__((address_space(3))) void*)((char*)sB + (i * 256 + w * 64) * 16),
                16, 0, 0);
        __syncthreads();

        s16x8 af[4], bf[2];
        #pragma unroll
        for (int mi = 0; mi < 4; ++mi) {
            f32x4 f0 = *(const f32x4*)((const char*)sA + offA[mi][0]);
            f32x4 f1 = *(const f32x4*)((const char*)sA + offA[mi][1]);
            s16x8 a;
            #pragma unroll
            for (int j = 0; j < 4; ++j) { a[j] = f2bf(f0[j]); a[4 + j] = f2bf(f1[j]); }
            af[mi] = a;
        }
        #pragma unroll
        for (int ni = 0; ni < 2; ++ni)
            bf[ni] = *(const s16x8*)((const char*)sB + offB[ni]);

        #pragma unroll
        for (int mi = 0; mi < 4; ++mi)
            #pragma unroll
            for (int ni = 0; ni < 2; ++ni)
                acc[mi][ni] = __builtin_amdgcn_mfma_f32_16x16x32_bf16(
                    af[mi], bf[ni], acc[mi][ni], 0, 0, 0);
        __syncthreads();
    }

    if (t < 64) e_sm[t] = 0.f;
    __syncthreads();

    float wfv[2];
    #pragma unroll
    for (int ni = 0; ni < 2; ++ni)
        wfv[ni] = Wf[aBase + w * 32 + ni * 16 + r];

    #pragma unroll
    for (int mi = 0; mi < 4; ++mi) {
        #pragma unroll
        for (int reg = 0; reg < 4; ++reg) {
            int lrow = mi * 16 + q * 4 + reg;
            int gm = mBase + lrow;
            int b = gm / NN;
            const float* a2 = att2 + b * ATT + aBase + w * 32;
            float rs = 0.f;
            #pragma unroll
            for (int ni = 0; ni < 2; ++ni) {
                float v = acc[mi][ni][reg] + a2[ni * 16 + r];
                rs += fmaxf(v, 0.f) * wfv[ni];
            }
            rs += __shfl_xor(rs, 1);
            rs += __shfl_xor(rs, 2);
            rs += __shfl_xor(rs, 4);
            rs += __shfl_xor(rs, 8);
            if (r == 0) atomicAdd(&e_sm[lrow], rs);
        }
    }
    __syncthreads();
    if (t < 64)
        e_part[(size_t)aBlk * MM + mBase + t] = e_sm[t];
}

// ---------------------------------------------------------------------------
// k2a: softmax over N per batch -> alpha (out tail + ws copy); nparts variable
// ---------------------------------------------------------------------------
__global__ void softmax_kernel(const float* __restrict__ e_part,
                               const float* __restrict__ b_full,
                               float* __restrict__ out,
                               float* __restrict__ alpha_ws,
                               int nparts) {
    const int b = blockIdx.x;
    const int t = threadIdx.x;      // 256
    __shared__ float sm[256];

    float v = -3.0e38f;
    if (t < NN) {
        int gm = b * NN + t;
        float s = b_full[0];
        for (int p = 0; p < nparts; ++p) s += e_part[(size_t)p * MM + gm];
        v = s;
    }
    sm[t] = v;
    __syncthreads();
    for (int s = 128; s > 0; s >>= 1) {
        if (t < s) sm[t] = fmaxf(sm[t], sm[t + s]);
        __syncthreads();
    }
    float mx = sm[0];
    __syncthreads();
    float ex = (t < NN) ? __expf(v - mx) : 0.f;
    sm[t] = ex;
    __syncthreads();
    for (int s = 128; s > 0; s >>= 1) {
        if (t < s) sm[t] += sm[t + s];
        __syncthreads();
    }
    float inv = 1.0f / sm[0];
    if (t < NN) {
        float a = ex * inv;
        out[BB * ENC + b * NN + t] = a;
        alpha_ws[b * NN + t] = a;
    }
}

// ---------------------------------------------------------------------------
// k2b MAIN: awe from bf16 encoder copy. (128,2) x 256; lane = 4 cols (8B loads).
// ---------------------------------------------------------------------------
__global__ __launch_bounds__(256)
void awe_bf16_kernel(const unsigned short* __restrict__ encb,
                     const float* __restrict__ alpha_ws,
                     float* __restrict__ out) {
    const int b = blockIdx.x, chunk = blockIdx.y;
    const int t = threadIdx.x;
    __shared__ float al[NN];
    if (t < NN) al[t] = alpha_ws[b * NN + t];
    __syncthreads();

    const unsigned short* ep = encb + (size_t)b * NN * ENC + chunk * 1024 + t * 4;
    f32x4 acc0 = {}, acc1 = {}, acc2 = {}, acc3 = {};
    #pragma unroll 2
    for (int n = 0; n < NN; n += 4) {   // 196 = 4*49 exact
        u16x4 v0 = *(const u16x4*)(ep + (size_t)(n + 0) * ENC);
        u16x4 v1 = *(const u16x4*)(ep + (size_t)(n + 1) * ENC);
        u16x4 v2 = *(const u16x4*)(ep + (size_t)(n + 2) * ENC);
        u16x4 v3 = *(const u16x4*)(ep + (size_t)(n + 3) * ENC);
        #pragma unroll
        for (int j = 0; j < 4; ++j) {
            acc0[j] += bf2f(v0[j]) * al[n];
            acc1[j] += bf2f(v1[j]) * al[n + 1];
            acc2[j] += bf2f(v2[j]) * al[n + 2];
            acc3[j] += bf2f(v3[j]) * al[n + 3];
        }
    }
    f32x4 s = (acc0 + acc1) + (acc2 + acc3);
    *(f32x4*)(out + (size_t)b * ENC + chunk * 1024 + t * 4) = s;
}

// ---------------------------------------------------------------------------
// k2b FALLBACK: awe from fp32 encoder
// ---------------------------------------------------------------------------
__global__ __launch_bounds__(256)
void awe_kernel(const float* __restrict__ enc,
                const float* __restrict__ alpha_ws,
                float* __restrict__ out) {
    const int b = blockIdx.x, chunk = blockIdx.y;
    const int t = threadIdx.x;
    __shared__ float al[NN];
    if (t < NN) al[t] = alpha_ws[b * NN + t];
    __syncthreads();

    const float* ep = enc + (size_t)b * NN * ENC + chunk * 1024 + t * 4;
    f32x4 acc0 = {}, acc1 = {}, acc2 = {}, acc3 = {};
    #pragma unroll 2
    for (int n = 0; n < NN; n += 4) {
        f32x4 v0 = *(const f32x4*)(ep + (size_t)(n + 0) * ENC);
        f32x4 v1 = *(const f32x4*)(ep + (size_t)(n + 1) * ENC);
        f32x4 v2 = *(const f32x4*)(ep + (size_t)(n + 2) * ENC);
        f32x4 v3 = *(const f32x4*)(ep + (size_t)(n + 3) * ENC);
        acc0 += v0 * al[n];
        acc1 += v1 * al[n + 1];
        acc2 += v2 * al[n + 2];
        acc3 += v3 * al[n + 3];
    }
    f32x4 s = (acc0 + acc1) + (acc2 + acc3);
    *(f32x4*)(out + (size_t)b * ENC + chunk * 1024 + t * 4) = s;
}

// ---------------------------------------------------------------------------
extern "C" void kernel_launch(void* const* d_in, const int* in_sizes, int n_in,
                              void* d_out, int out_size, void* d_ws, size_t ws_size,
                              hipStream_t stream) {
    const float* enc    = (const float*)d_in[0];
    const float* dec    = (const float*)d_in[1];
    const float* W_enc  = (const float*)d_in[2];
    const float* b_enc  = (const float*)d_in[3];
    const float* W_dec  = (const float*)d_in[4];
    const float* b_dec  = (const float*)d_in[5];
    const float* W_full = (const float*)d_in[6];
    const float* b_full = (const float*)d_in[7];
    float* out = (float*)d_out;   // [128*2048 awe | 128*196 alpha]

    char* ws = (char*)d_ws;
    unsigned short* Wt = (unsigned short*)ws;                        // 2 MB
    float* att2     = (float*)(ws + 2097152);                        // 256 KB
    float* e_part   = (float*)(ws + 2359296);                        // 4*MM*4 = 392 KB
    float* alpha_ws = (float*)(ws + 2760704);                        // 98 KB
    unsigned short* encb = (unsigned short*)(ws + 3145728);          // 98 MB
    const size_t WS_NEED = 3145728 + (size_t)MM * ENC * 2;           // ~101 MB

    transpose_convert_kernel<<<dim3(ATT / 32, ENC / 32), 256, 0, stream>>>(W_enc, Wt);
    att2_kernel<<<dim3(BB, 8), 256, 0, stream>>>(dec, W_dec, b_dec, b_enc, att2);

    if (ws_size >= WS_NEED) {
        enc_cvt_kernel<<<MM, 256, 0, stream>>>(enc, encb);
        gemm_bf16_kernel<<<dim3(ATT / BA, MM / BM), 512, 0, stream>>>(encb, Wt, att2, W_full, e_part);
        softmax_kernel<<<BB, 256, 0, stream>>>(e_part, b_full, out, alpha_ws, 2);
        awe_bf16_kernel<<<dim3(BB, 2), 256, 0, stream>>>(encb, alpha_ws, out);
    } else {
        gemm_e_kernel<<<dim3(4, MM / 64), 256, 0, stream>>>(enc, Wt, att2, W_full, e_part);
        softmax_kernel<<<BB, 256, 0, stream>>>(e_part, b_full, out, alpha_ws, 4);
        awe_kernel<<<dim3(BB, 2), 256, 0, stream>>>(enc, alpha_ws, out);
    }
}

// Round 9
// 428.673 us; speedup vs baseline: 1.0319x; 1.0319x over previous
//
#include <hip/hip_runtime.h>
#include <hip/hip_bf16.h>

// Problem constants
#define BB   128
#define NN   196
#define MM   (BB*NN)      // 25088
#define ENC  2048
#define ATT  512
#define DEC  512
#define BK   32
#define KSTEPS (ENC/BK)   // 64
#define BM   256          // gemm m-rows per block (R8: 256 -> grid 196 blocks, 1 round, no tail)
#define BA   256          // gemm a-cols per block

using f32x4 = __attribute__((ext_vector_type(4))) float;
using s16x8 = __attribute__((ext_vector_type(8))) short;
using u16x4 = __attribute__((ext_vector_type(4))) unsigned short;
using u16x8 = __attribute__((ext_vector_type(8))) unsigned short;

__device__ __forceinline__ short f2bf(float f) {
    union { __hip_bfloat16 h; short s; } u;
    u.h = __float2bfloat16(f);
    return u.s;
}
__device__ __forceinline__ float bf2f(unsigned short u) {
    union { unsigned int i; float f; } v;
    v.i = ((unsigned int)u) << 16;
    return v.f;
}

// LDS byte offset (32-bit) of a generic pointer into __shared__
__device__ __forceinline__ unsigned lds_addr(void* p) {
    return (unsigned)(unsigned long long)(__attribute__((address_space(3))) void*)p;
}

// inline-asm ds_read_b128: keeps the compiler's LDS-dependency tracker from
// inserting a vmcnt(0) drain before fragment reads (R1 regression cause).
// "=&v" early-clobber: dest tuple must not overlap the live address VGPR.
#define DSR(dst, base, imm) \
    asm volatile("ds_read_b128 %0, %1 offset:" #imm : "=&v"(dst) : "v"(base))

// ---------------------------------------------------------------------------
// k0a: transpose+convert W_enc [2048][512] f32 -> Wt [512][2048] bf16
// ---------------------------------------------------------------------------
__global__ void transpose_convert_kernel(const float* __restrict__ W,
                                         unsigned short* __restrict__ Wt) {
    __shared__ float tile[32][33];
    const int a0 = blockIdx.x * 32;
    const int k0 = blockIdx.y * 32;
    const int tx = threadIdx.x & 31, ty = threadIdx.x >> 5;
    #pragma unroll
    for (int i = 0; i < 32; i += 8)
        tile[ty + i][tx] = W[(size_t)(k0 + ty + i) * ATT + a0 + tx];
    __syncthreads();
    #pragma unroll
    for (int i = 0; i < 32; i += 8) {
        union { __hip_bfloat16 h; unsigned short u; } v;
        v.h = __float2bfloat16(tile[tx][ty + i]);
        Wt[(size_t)(a0 + ty + i) * ENC + k0 + tx] = v.u;
    }
}

// ---------------------------------------------------------------------------
// k0c: convert encoder_out fp32 -> bf16 (row per block; 256 thr x 8 elem)
// ---------------------------------------------------------------------------
__global__ __launch_bounds__(256)
void enc_cvt_kernel(const float* __restrict__ enc,
                    unsigned short* __restrict__ encb) {
    const size_t row = blockIdx.x;
    const int t = threadIdx.x;
    const float* in = enc + row * ENC + t * 8;
    f32x4 a = *(const f32x4*)in;
    f32x4 b = *(const f32x4*)(in + 4);
    u16x8 o;
    #pragma unroll
    for (int j = 0; j < 4; ++j) {
        o[j]     = (unsigned short)f2bf(a[j]);
        o[4 + j] = (unsigned short)f2bf(b[j]);
    }
    *(u16x8*)(encb + row * ENC + t * 8) = o;
}

// ---------------------------------------------------------------------------
// k0b: att2[b][a] = dec[b] @ W_dec[:,a] + b_dec[a] + b_enc[a]
// ---------------------------------------------------------------------------
__global__ void att2_kernel(const float* __restrict__ dec,
                            const float* __restrict__ Wd,
                            const float* __restrict__ bd,
                            const float* __restrict__ benc,
                            float* __restrict__ att2) {
    const int b  = blockIdx.x;
    const int c0 = blockIdx.y * 64;
    const int t  = threadIdx.x;
    const int cl = t & 63, kg = t >> 6;
    __shared__ float sdec[DEC];
    __shared__ float red[4][64];
    sdec[t]       = dec[b * DEC + t];
    sdec[t + 256] = dec[b * DEC + t + 256];
    __syncthreads();
    float acc = 0.f;
    const float* wp = Wd + c0 + cl;
    #pragma unroll 8
    for (int k = kg * 128; k < kg * 128 + 128; ++k)
        acc += sdec[k] * wp[(size_t)k * ATT];
    red[kg][cl] = acc;
    __syncthreads();
    if (t < 64) {
        float s = red[0][t] + red[1][t] + red[2][t] + red[3][t];
        att2[b * ATT + c0 + t] = s + bd[c0 + t] + benc[c0 + t];
    }
}

// ---------------------------------------------------------------------------
// k1 MAIN: fused GEMM + bias + relu + dot(W_full) -> e_part[2][MM]
//   R(polish-8): GRID-TAIL theory. All three schedules (drain-0 dbuf,
//   static dbuf, counted-vmcnt) landed at ~113us -> the binding constraint
//   was never the drain: 392 blocks / 256 CUs = 1.53 rounds means half
//   the CUs run 2 blocks serially (35-50% straggler tail no schedule can
//   fix; also why R4 ran at 5.3 TB/s effective vs R0's 8.2 balanced).
//   Fix: BM=256 x BA=256 -> grid (2,98) = 196 blocks <= 256 CUs: ONE
//   round, zero tail, and staged traffic drops 598 -> 402 MB (A 206 +
//   B 196, lowest yet). 512 thr, 8 waves 2m x 4a, per-wave 128m x 64a
//   (8x4 frags, acc 128 VGPR; launch_bounds(512,2) -> 256-VGPR budget).
//   Counted-vmcnt pipeline kept (4 loads/thread/stage -> vmcnt(4));
//   fragment-linear LDS (0 conflicts); raw barriers; asm ds_read +
//   lgkmcnt(0) + sched_barrier(0) (rule #18). LDS 65 KB -> 1 block/CU.
// ---------------------------------------------------------------------------
__global__ __launch_bounds__(512, 2)
void gemm_bf16_kernel(const unsigned short* __restrict__ encb,
                      const unsigned short* __restrict__ Wt,
                      const float* __restrict__ att2,
                      const float* __restrict__ Wf,
                      float* __restrict__ e_part) {
    // fragment-linear: A slot = mi*64 + lane (mi 0..15), 16 B/slot
    //                  B slot = ni*64 + lane (ni 0..15)
    __shared__ unsigned short sA0[1024 * 8];    // 16 KB
    __shared__ unsigned short sA1[1024 * 8];    // 16 KB
    __shared__ unsigned short sB0[1024 * 8];    // 16 KB
    __shared__ unsigned short sB1[1024 * 8];    // 16 KB
    __shared__ float e_sm[BM];

    const int t    = threadIdx.x;      // 0..511
    const int lane = t & 63;
    const int w    = t >> 6;           // 0..7
    const int wm   = w >> 2;           // 0..1  (m wave-row; 128 rows each)
    const int wa   = w & 3;            // 0..3  (a wave-col; 64 cols each)
    const int aBlk  = blockIdx.x;      // 0..1
    const int mBase = blockIdx.y * BM; // 98 tiles
    const int aBase = aBlk * BA;
    const int r = lane & 15, q = lane >> 4;

    if (t < BM) e_sm[t] = 0.f;         // visible long before epilogue use

    // --- staging sources (pre-swizzled global addresses, fragment order) ---
    // A slot s=i*512+t (s 0..1023): mi=s>>6, row=mi*16+(s&15), kchunk=((s>>4)&3)*8
    const unsigned short* gA[2];
    #pragma unroll
    for (int i = 0; i < 2; ++i) {
        int s = i * 512 + t;
        gA[i] = encb + (size_t)(mBase + ((s >> 6) << 4) + (s & 15)) * ENC + ((s >> 4) & 3) * 8;
    }
    // B slot s=i*512+t (s 0..1023): ni=s>>6, row=ni*16+(s&15), kchunk=((s>>4)&3)*8
    const unsigned short* gB[2];
    #pragma unroll
    for (int i = 0; i < 2; ++i) {
        int s = i * 512 + t;
        gB[i] = Wt + (size_t)(aBase + ((s >> 6) << 4) + (s & 15)) * ENC + ((s >> 4) & 3) * 8;
    }

    // per-thread LDS read bases (byte offsets)
    const unsigned a0base = lds_addr(sA0) + (unsigned)(wm * 8192 + lane * 16);
    const unsigned a1base = lds_addr(sA1) + (unsigned)(wm * 8192 + lane * 16);
    const unsigned b0base = lds_addr(sB0) + (unsigned)(wa * 4096 + lane * 16);
    const unsigned b1base = lds_addr(sB1) + (unsigned)(wa * 4096 + lane * 16);

    f32x4 acc[8][4] = {};

    auto stage = [&](unsigned short* bA, unsigned short* bB, int ks) {
        #pragma unroll
        for (int i = 0; i < 2; ++i)
            __builtin_amdgcn_global_load_lds(
                (const __attribute__((address_space(1))) void*)(gA[i] + (size_t)ks * BK),
                (__attribute__((address_space(3))) void*)((char*)bA + (i * 512 + t) * 16),
                16, 0, 0);
        #pragma unroll
        for (int i = 0; i < 2; ++i)
            __builtin_amdgcn_global_load_lds(
                (const __attribute__((address_space(1))) void*)(gB[i] + (size_t)ks * BK),
                (__attribute__((address_space(3))) void*)((char*)bB + (i * 512 + t) * 16),
                16, 0, 0);
    };

    auto compute = [&](unsigned abase, unsigned bbase) {
        s16x8 af0, af1, af2, af3, af4, af5, af6, af7;
        s16x8 bf0, bf1, bf2, bf3;
        DSR(bf0, bbase, 0);
        DSR(bf1, bbase, 1024);
        DSR(bf2, bbase, 2048);
        DSR(bf3, bbase, 3072);
        DSR(af0, abase, 0);
        DSR(af1, abase, 1024);
        DSR(af2, abase, 2048);
        DSR(af3, abase, 3072);
        DSR(af4, abase, 4096);
        DSR(af5, abase, 5120);
        DSR(af6, abase, 6144);
        DSR(af7, abase, 7168);
        asm volatile("s_waitcnt lgkmcnt(0)" ::: "memory");
        __builtin_amdgcn_sched_barrier(0);
        acc[0][0] = __builtin_amdgcn_mfma_f32_16x16x32_bf16(af0, bf0, acc[0][0], 0, 0, 0);
        acc[0][1] = __builtin_amdgcn_mfma_f32_16x16x32_bf16(af0, bf1, acc[0][1], 0, 0, 0);
        acc[0][2] = __builtin_amdgcn_mfma_f32_16x16x32_bf16(af0, bf2, acc[0][2], 0, 0, 0);
        acc[0][3] = __builtin_amdgcn_mfma_f32_16x16x32_bf16(af0, bf3, acc[0][3], 0, 0, 0);
        acc[1][0] = __builtin_amdgcn_mfma_f32_16x16x32_bf16(af1, bf0, acc[1][0], 0, 0, 0);
        acc[1][1] = __builtin_amdgcn_mfma_f32_16x16x32_bf16(af1, bf1, acc[1][1], 0, 0, 0);
        acc[1][2] = __builtin_amdgcn_mfma_f32_16x16x32_bf16(af1, bf2, acc[1][2], 0, 0, 0);
        acc[1][3] = __builtin_amdgcn_mfma_f32_16x16x32_bf16(af1, bf3, acc[1][3], 0, 0, 0);
        acc[2][0] = __builtin_amdgcn_mfma_f32_16x16x32_bf16(af2, bf0, acc[2][0], 0, 0, 0);
        acc[2][1] = __builtin_amdgcn_mfma_f32_16x16x32_bf16(af2, bf1, acc[2][1], 0, 0, 0);
        acc[2][2] = __builtin_amdgcn_mfma_f32_16x16x32_bf16(af2, bf2, acc[2][2], 0, 0, 0);
        acc[2][3] = __builtin_amdgcn_mfma_f32_16x16x32_bf16(af2, bf3, acc[2][3], 0, 0, 0);
        acc[3][0] = __builtin_amdgcn_mfma_f32_16x16x32_bf16(af3, bf0, acc[3][0], 0, 0, 0);
        acc[3][1] = __builtin_amdgcn_mfma_f32_16x16x32_bf16(af3, bf1, acc[3][1], 0, 0, 0);
        acc[3][2] = __builtin_amdgcn_mfma_f32_16x16x32_bf16(af3, bf2, acc[3][2], 0, 0, 0);
        acc[3][3] = __builtin_amdgcn_mfma_f32_16x16x32_bf16(af3, bf3, acc[3][3], 0, 0, 0);
        acc[4][0] = __builtin_amdgcn_mfma_f32_16x16x32_bf16(af4, bf0, acc[4][0], 0, 0, 0);
        acc[4][1] = __builtin_amdgcn_mfma_f32_16x16x32_bf16(af4, bf1, acc[4][1], 0, 0, 0);
        acc[4][2] = __builtin_amdgcn_mfma_f32_16x16x32_bf16(af4, bf2, acc[4][2], 0, 0, 0);
        acc[4][3] = __builtin_amdgcn_mfma_f32_16x16x32_bf16(af4, bf3, acc[4][3], 0, 0, 0);
        acc[5][0] = __builtin_amdgcn_mfma_f32_16x16x32_bf16(af5, bf0, acc[5][0], 0, 0, 0);
        acc[5][1] = __builtin_amdgcn_mfma_f32_16x16x32_bf16(af5, bf1, acc[5][1], 0, 0, 0);
        acc[5][2] = __builtin_amdgcn_mfma_f32_16x16x32_bf16(af5, bf2, acc[5][2], 0, 0, 0);
        acc[5][3] = __builtin_amdgcn_mfma_f32_16x16x32_bf16(af5, bf3, acc[5][3], 0, 0, 0);
        acc[6][0] = __builtin_amdgcn_mfma_f32_16x16x32_bf16(af6, bf0, acc[6][0], 0, 0, 0);
        acc[6][1] = __builtin_amdgcn_mfma_f32_16x16x32_bf16(af6, bf1, acc[6][1], 0, 0, 0);
        acc[6][2] = __builtin_amdgcn_mfma_f32_16x16x32_bf16(af6, bf2, acc[6][2], 0, 0, 0);
        acc[6][3] = __builtin_amdgcn_mfma_f32_16x16x32_bf16(af6, bf3, acc[6][3], 0, 0, 0);
        acc[7][0] = __builtin_amdgcn_mfma_f32_16x16x32_bf16(af7, bf0, acc[7][0], 0, 0, 0);
        acc[7][1] = __builtin_amdgcn_mfma_f32_16x16x32_bf16(af7, bf1, acc[7][1], 0, 0, 0);
        acc[7][2] = __builtin_amdgcn_mfma_f32_16x16x32_bf16(af7, bf2, acc[7][2], 0, 0, 0);
        acc[7][3] = __builtin_amdgcn_mfma_f32_16x16x32_bf16(af7, bf3, acc[7][3], 0, 0, 0);
    };

    // counted-vmcnt 2-phase pipeline. 4 loads/wave per stage.
    // stage(next) -> vmcnt(4) [cur's 4 done, next's 4 in flight] -> barrier
    // -> compute(cur) -> barrier [all waves done reading cur before it is
    // overwritten next step].
    stage(sA0, sB0, 0);
    #pragma unroll 1
    for (int ks = 0; ks < KSTEPS - 2; ks += 2) {
        stage(sA1, sB1, ks + 1);
        asm volatile("s_waitcnt vmcnt(4)" ::: "memory");
        __builtin_amdgcn_s_barrier();
        compute(a0base, b0base);
        __builtin_amdgcn_s_barrier();
        stage(sA0, sB0, ks + 2);
        asm volatile("s_waitcnt vmcnt(4)" ::: "memory");
        __builtin_amdgcn_s_barrier();
        compute(a1base, b1base);
        __builtin_amdgcn_s_barrier();
    }
    // epilogue: steps KSTEPS-2 (in sA0/sB0, in flight) and KSTEPS-1
    stage(sA1, sB1, KSTEPS - 1);
    asm volatile("s_waitcnt vmcnt(4)" ::: "memory");
    __builtin_amdgcn_s_barrier();
    compute(a0base, b0base);
    __builtin_amdgcn_s_barrier();
    asm volatile("s_waitcnt vmcnt(0)" ::: "memory");
    __builtin_amdgcn_s_barrier();
    compute(a1base, b1base);

    // --- epilogue: e contribution = sum_a relu(att1 + att2) * Wf ---
    float wfv[4];
    #pragma unroll
    for (int ni = 0; ni < 4; ++ni)
        wfv[ni] = Wf[aBase + wa * 64 + ni * 16 + r];

    #pragma unroll
    for (int mi = 0; mi < 8; ++mi) {
        #pragma unroll
        for (int reg = 0; reg < 4; ++reg) {
            int lrow = wm * 128 + mi * 16 + q * 4 + reg;  // C/D: row=(lane>>4)*4+reg
            int gm = mBase + lrow;
            int b = gm / NN;
            const float* a2 = att2 + b * ATT + aBase + wa * 64;
            float rs = 0.f;
            #pragma unroll
            for (int ni = 0; ni < 4; ++ni) {
                float v = acc[mi][ni][reg] + a2[ni * 16 + r];  // col = lane&15
                rs += fmaxf(v, 0.f) * wfv[ni];
            }
            rs += __shfl_xor(rs, 1);
            rs += __shfl_xor(rs, 2);
            rs += __shfl_xor(rs, 4);
            rs += __shfl_xor(rs, 8);
            if (r == 0) atomicAdd(&e_sm[lrow], rs);
        }
    }
    __syncthreads();
    if (t < BM)
        e_part[(size_t)aBlk * MM + mBase + t] = e_sm[t];
}

// ---------------------------------------------------------------------------
// k1 FALLBACK (R4): 64m x 128a fp32-A gemm -> e_part[4][MM]
// ---------------------------------------------------------------------------
__global__ __launch_bounds__(256, 5)
void gemm_e_kernel(const float* __restrict__ enc,
                   const unsigned short* __restrict__ Wt,
                   const float* __restrict__ att2,
                   const float* __restrict__ Wf,
                   float* __restrict__ e_part) {
    __shared__ float sA[64 * 32];
    __shared__ unsigned short sB[128 * 32];
    __shared__ float e_sm[64];

    const int t    = threadIdx.x;
    const int lane = t & 63;
    const int w    = t >> 6;
    const int aBlk  = blockIdx.x;
    const int mBase = blockIdx.y * 64;
    const int aBase = aBlk * 128;
    const int r = lane & 15, q = lane >> 4;

    const float* gA[2];
    #pragma unroll
    for (int i = 0; i < 2; ++i) {
        int s = i * 256 + t;
        int row = s >> 3, ck = s & 7;
        int g = ck ^ (row & 7);
        gA[i] = enc + (size_t)(mBase + row) * ENC + g * 4;
    }
    const unsigned short* gB[2];
    #pragma unroll
    for (int i = 0; i < 2; ++i) {
        int s = i * 256 + t;
        int row = s >> 2, ck = s & 3;
        int g = ck ^ ((row & 3) ^ ((row >> 2) & 3));
        gB[i] = Wt + (size_t)(aBase + row) * ENC + g * 8;
    }

    int offA[4][2];
    #pragma unroll
    for (int mi = 0; mi < 4; ++mi) {
        int row = mi * 16 + r;
        offA[mi][0] = row * 128 + ((2 * q)     ^ (row & 7)) * 16;
        offA[mi][1] = row * 128 + ((2 * q + 1) ^ (row & 7)) * 16;
    }
    int offB[2];
    #pragma unroll
    for (int ni = 0; ni < 2; ++ni) {
        int col = w * 32 + ni * 16 + r;
        offB[ni] = col * 64 + (q ^ ((col & 3) ^ ((col >> 2) & 3))) * 16;
    }

    f32x4 acc[4][2] = {};

    #pragma unroll 1
    for (int ks = 0; ks < KSTEPS; ++ks) {
        #pragma unroll
        for (int i = 0; i < 2; ++i)
            __builtin_amdgcn_global_load_lds(
                (const __attribute__((address_space(1))) void*)(gA[i] + (size_t)ks * BK),
                (__attribute__((address_space(3))) void*)((char*)sA + (i * 256 + w * 64) * 16),
                16, 0, 0);
        #pragma unroll
        for (int i = 0; i < 2; ++i)
            __builtin_amdgcn_global_load_lds(
                (const __attribute__((address_space(1))) void*)(gB[i] + (size_t)ks * BK),
                (__attribute__((address_space(3))) void*)((char*)sB + (i * 256 + w * 64) * 16),
                16, 0, 0);
        __syncthreads();

        s16x8 af[4], bf[2];
        #pragma unroll
        for (int mi = 0; mi < 4; ++mi) {
            f32x4 f0 = *(const f32x4*)((const char*)sA + offA[mi][0]);
            f32x4 f1 = *(const f32x4*)((const char*)sA + offA[mi][1]);
            s16x8 a;
            #pragma unroll
            for (int j = 0; j < 4; ++j) { a[j] = f2bf(f0[j]); a[4 + j] = f2bf(f1[j]); }
            af[mi] = a;
        }
        #pragma unroll
        for (int ni = 0; ni < 2; ++ni)
            bf[ni] = *(const s16x8*)((const char*)sB + offB[ni]);

        #pragma unroll
        for (int mi = 0; mi < 4; ++mi)
            #pragma unroll
            for (int ni = 0; ni < 2; ++ni)
                acc[mi][ni] = __builtin_amdgcn_mfma_f32_16x16x32_bf16(
                    af[mi], bf[ni], acc[mi][ni], 0, 0, 0);
        __syncthreads();
    }

    if (t < 64) e_sm[t] = 0.f;
    __syncthreads();

    float wfv[2];
    #pragma unroll
    for (int ni = 0; ni < 2; ++ni)
        wfv[ni] = Wf[aBase + w * 32 + ni * 16 + r];

    #pragma unroll
    for (int mi = 0; mi < 4; ++mi) {
        #pragma unroll
        for (int reg = 0; reg < 4; ++reg) {
            int lrow = mi * 16 + q * 4 + reg;
            int gm = mBase + lrow;
            int b = gm / NN;
            const float* a2 = att2 + b * ATT + aBase + w * 32;
            float rs = 0.f;
            #pragma unroll
            for (int ni = 0; ni < 2; ++ni) {
                float v = acc[mi][ni][reg] + a2[ni * 16 + r];
                rs += fmaxf(v, 0.f) * wfv[ni];
            }
            rs += __shfl_xor(rs, 1);
            rs += __shfl_xor(rs, 2);
            rs += __shfl_xor(rs, 4);
            rs += __shfl_xor(rs, 8);
            if (r == 0) atomicAdd(&e_sm[lrow], rs);
        }
    }
    __syncthreads();
    if (t < 64)
        e_part[(size_t)aBlk * MM + mBase + t] = e_sm[t];
}

// ---------------------------------------------------------------------------
// k2a: softmax over N per batch -> alpha (out tail + ws copy); nparts variable
// ---------------------------------------------------------------------------
__global__ void softmax_kernel(const float* __restrict__ e_part,
                               const float* __restrict__ b_full,
                               float* __restrict__ out,
                               float* __restrict__ alpha_ws,
                               int nparts) {
    const int b = blockIdx.x;
    const int t = threadIdx.x;      // 256
    __shared__ float sm[256];

    float v = -3.0e38f;
    if (t < NN) {
        int gm = b * NN + t;
        float s = b_full[0];
        for (int p = 0; p < nparts; ++p) s += e_part[(size_t)p * MM + gm];
        v = s;
    }
    sm[t] = v;
    __syncthreads();
    for (int s = 128; s > 0; s >>= 1) {
        if (t < s) sm[t] = fmaxf(sm[t], sm[t + s]);
        __syncthreads();
    }
    float mx = sm[0];
    __syncthreads();
    float ex = (t < NN) ? __expf(v - mx) : 0.f;
    sm[t] = ex;
    __syncthreads();
    for (int s = 128; s > 0; s >>= 1) {
        if (t < s) sm[t] += sm[t + s];
        __syncthreads();
    }
    float inv = 1.0f / sm[0];
    if (t < NN) {
        float a = ex * inv;
        out[BB * ENC + b * NN + t] = a;
        alpha_ws[b * NN + t] = a;
    }
}

// ---------------------------------------------------------------------------
// k2b MAIN: awe from bf16 encoder copy. (128,2) x 256; lane = 4 cols (8B loads).
// ---------------------------------------------------------------------------
__global__ __launch_bounds__(256)
void awe_bf16_kernel(const unsigned short* __restrict__ encb,
                     const float* __restrict__ alpha_ws,
                     float* __restrict__ out) {
    const int b = blockIdx.x, chunk = blockIdx.y;
    const int t = threadIdx.x;
    __shared__ float al[NN];
    if (t < NN) al[t] = alpha_ws[b * NN + t];
    __syncthreads();

    const unsigned short* ep = encb + (size_t)b * NN * ENC + chunk * 1024 + t * 4;
    f32x4 acc0 = {}, acc1 = {}, acc2 = {}, acc3 = {};
    #pragma unroll 2
    for (int n = 0; n < NN; n += 4) {   // 196 = 4*49 exact
        u16x4 v0 = *(const u16x4*)(ep + (size_t)(n + 0) * ENC);
        u16x4 v1 = *(const u16x4*)(ep + (size_t)(n + 1) * ENC);
        u16x4 v2 = *(const u16x4*)(ep + (size_t)(n + 2) * ENC);
        u16x4 v3 = *(const u16x4*)(ep + (size_t)(n + 3) * ENC);
        #pragma unroll
        for (int j = 0; j < 4; ++j) {
            acc0[j] += bf2f(v0[j]) * al[n];
            acc1[j] += bf2f(v1[j]) * al[n + 1];
            acc2[j] += bf2f(v2[j]) * al[n + 2];
            acc3[j] += bf2f(v3[j]) * al[n + 3];
        }
    }
    f32x4 s = (acc0 + acc1) + (acc2 + acc3);
    *(f32x4*)(out + (size_t)b * ENC + chunk * 1024 + t * 4) = s;
}

// ---------------------------------------------------------------------------
// k2b FALLBACK: awe from fp32 encoder
// ---------------------------------------------------------------------------
__global__ __launch_bounds__(256)
void awe_kernel(const float* __restrict__ enc,
                const float* __restrict__ alpha_ws,
                float* __restrict__ out) {
    const int b = blockIdx.x, chunk = blockIdx.y;
    const int t = threadIdx.x;
    __shared__ float al[NN];
    if (t < NN) al[t] = alpha_ws[b * NN + t];
    __syncthreads();

    const float* ep = enc + (size_t)b * NN * ENC + chunk * 1024 + t * 4;
    f32x4 acc0 = {}, acc1 = {}, acc2 = {}, acc3 = {};
    #pragma unroll 2
    for (int n = 0; n < NN; n += 4) {
        f32x4 v0 = *(const f32x4*)(ep + (size_t)(n + 0) * ENC);
        f32x4 v1 = *(const f32x4*)(ep + (size_t)(n + 1) * ENC);
        f32x4 v2 = *(const f32x4*)(ep + (size_t)(n + 2) * ENC);
        f32x4 v3 = *(const f32x4*)(ep + (size_t)(n + 3) * ENC);
        acc0 += v0 * al[n];
        acc1 += v1 * al[n + 1];
        acc2 += v2 * al[n + 2];
        acc3 += v3 * al[n + 3];
    }
    f32x4 s = (acc0 + acc1) + (acc2 + acc3);
    *(f32x4*)(out + (size_t)b * ENC + chunk * 1024 + t * 4) = s;
}

// ---------------------------------------------------------------------------
extern "C" void kernel_launch(void* const* d_in, const int* in_sizes, int n_in,
                              void* d_out, int out_size, void* d_ws, size_t ws_size,
                              hipStream_t stream) {
    const float* enc    = (const float*)d_in[0];
    const float* dec    = (const float*)d_in[1];
    const float* W_enc  = (const float*)d_in[2];
    const float* b_enc  = (const float*)d_in[3];
    const float* W_dec  = (const float*)d_in[4];
    const float* b_dec  = (const float*)d_in[5];
    const float* W_full = (const float*)d_in[6];
    const float* b_full = (const float*)d_in[7];
    float* out = (float*)d_out;   // [128*2048 awe | 128*196 alpha]

    char* ws = (char*)d_ws;
    unsigned short* Wt = (unsigned short*)ws;                        // 2 MB
    float* att2     = (float*)(ws + 2097152);                        // 256 KB
    float* e_part   = (float*)(ws + 2359296);                        // 4*MM*4 = 392 KB
    float* alpha_ws = (float*)(ws + 2760704);                        // 98 KB
    unsigned short* encb = (unsigned short*)(ws + 3145728);          // 98 MB
    const size_t WS_NEED = 3145728 + (size_t)MM * ENC * 2;           // ~101 MB

    transpose_convert_kernel<<<dim3(ATT / 32, ENC / 32), 256, 0, stream>>>(W_enc, Wt);
    att2_kernel<<<dim3(BB, 8), 256, 0, stream>>>(dec, W_dec, b_dec, b_enc, att2);

    if (ws_size >= WS_NEED) {
        enc_cvt_kernel<<<MM, 256, 0, stream>>>(enc, encb);
        gemm_bf16_kernel<<<dim3(ATT / BA, MM / BM), 512, 0, stream>>>(encb, Wt, att2, W_full, e_part);
        softmax_kernel<<<BB, 256, 0, stream>>>(e_part, b_full, out, alpha_ws, 2);
        awe_bf16_kernel<<<dim3(BB, 2), 256, 0, stream>>>(encb, alpha_ws, out);
    } else {
        gemm_e_kernel<<<dim3(4, MM / 64), 256, 0, stream>>>(enc, Wt, att2, W_full, e_part);
        softmax_kernel<<<BB, 256, 0, stream>>>(e_part, b_full, out, alpha_ws, 4);
        awe_kernel<<<dim3(BB, 2), 256, 0, stream>>>(enc, alpha_ws, out);
    }
}